// Round 3
// baseline (430.843 us; speedup 1.0000x reference)
//
#include <hip/hip_runtime.h>

#define T_TOKENS 2048
#define DIM 1024
#define ISZ 2048
#define NEXP 8
#define NPAIRS (T_TOKENS * 2)
#define CAP (NPAIRS + 256)
#define MAXTILES 24
#define BK 32
#define BM 256

typedef __attribute__((ext_vector_type(8))) short bf16x8;
typedef __attribute__((ext_vector_type(4))) float f32x4;

// ---------------- ws layout ----------------
constexpr size_t OFF_COUNTS  = 0;     // 32 B
constexpr size_t OFF_CURSOR  = 32;    // 32 B
constexpr size_t OFF_OFFSETS = 64;    // 32 B
constexpr size_t OFF_NTILES  = 96;    // 4 B
constexpr size_t OFF_TILE_E  = 128;   // MAXTILES*4
constexpr size_t OFF_TILE_R0 = OFF_TILE_E  + MAXTILES * 4;
constexpr size_t OFF_TILE_NR = OFF_TILE_R0 + MAXTILES * 4;   // end 416 < 1024
constexpr size_t OFF_TOPK_I = 1024;
constexpr size_t OFF_TOPK_W = OFF_TOPK_I + (size_t)NPAIRS * 4;
constexpr size_t OFF_ROW_T  = OFF_TOPK_W + (size_t)NPAIRS * 4;
constexpr size_t OFF_ROW_W  = OFF_ROW_T + (size_t)CAP * 4;
constexpr size_t OFF_TSLOT  = OFF_ROW_W + (size_t)CAP * 4;
constexpr size_t OFF_XG     = (OFF_TSLOT + (size_t)NPAIRS * 4 + 255) & ~(size_t)255;
constexpr size_t OFF_H      = OFF_XG + (size_t)CAP * DIM * 2;
constexpr size_t OFF_EO     = OFF_H + (size_t)CAP * ISZ * 2;
// total: OFF_EO + CAP*DIM*4  (~43 MB)

__device__ __forceinline__ ushort f2bf(float f) {
    union { float f; unsigned u; } v; v.f = f;
    unsigned u = v.u;
    u += 0x7FFFu + ((u >> 16) & 1u);   // RNE
    return (ushort)(u >> 16);
}

__device__ __forceinline__ bf16x8 cvt_frag(float4 a, float4 b) {
    bf16x8 r;
    r[0] = (short)f2bf(a.x); r[1] = (short)f2bf(a.y);
    r[2] = (short)f2bf(a.z); r[3] = (short)f2bf(a.w);
    r[4] = (short)f2bf(b.x); r[5] = (short)f2bf(b.y);
    r[6] = (short)f2bf(b.z); r[7] = (short)f2bf(b.w);
    return r;
}

// async global -> LDS, 16B per lane. LDS dest must be wave-uniform base
// (HW writes base + lane*16); global src is per-lane.
__device__ __forceinline__ void gl_lds16(const void* g, void* l) {
    __builtin_amdgcn_global_load_lds(
        (__attribute__((address_space(1))) void*)(unsigned long long)g,
        (__attribute__((address_space(3))) void*)l,
        16, 0, 0);
}

// ---------------- router ----------------
__global__ void router_kernel(const float* __restrict__ x,
                              const float* __restrict__ gw,
                              float* __restrict__ logits_out,
                              int* __restrict__ topk_idx,
                              float* __restrict__ topk_w,
                              int* __restrict__ counts) {
    int gwave = (int)((blockIdx.x * blockDim.x + threadIdx.x) >> 6);
    int lane = threadIdx.x & 63;
    if (gwave >= T_TOKENS) return;
    const float* xr = x + (size_t)gwave * DIM;
    float xv[16];
#pragma unroll
    for (int i = 0; i < 16; i++) xv[i] = xr[i * 64 + lane];
    float lg[8];
#pragma unroll
    for (int e = 0; e < 8; e++) {
        const float* g = gw + e * DIM;
        float s = 0.f;
#pragma unroll
        for (int i = 0; i < 16; i++) s += xv[i] * g[i * 64 + lane];
#pragma unroll
        for (int off = 32; off > 0; off >>= 1) s += __shfl_xor(s, off, 64);
        lg[e] = s;
    }
    if (lane == 0) {
#pragma unroll
        for (int e = 0; e < 8; e++) logits_out[gwave * 8 + e] = lg[e];
        int e0 = 0; float l0 = lg[0];
#pragma unroll
        for (int e = 1; e < 8; e++) if (lg[e] > l0) { l0 = lg[e]; e0 = e; }
        int e1 = -1; float l1 = -1e30f;
#pragma unroll
        for (int e = 0; e < 8; e++) if (e != e0 && lg[e] > l1) { l1 = lg[e]; e1 = e; }
        float w0 = 1.f / (1.f + __expf(l1 - l0));
        float w1 = 1.f - w0;
        topk_idx[gwave * 2] = e0; topk_idx[gwave * 2 + 1] = e1;
        topk_w[gwave * 2] = w0;  topk_w[gwave * 2 + 1] = w1;
        atomicAdd(&counts[e0], 1);
        atomicAdd(&counts[e1], 1);
    }
}

// offsets + tile map (M=256 row tiles across experts)
__global__ void scan_kernel(const int* __restrict__ counts, int* __restrict__ offsets,
                            int* __restrict__ tile_e, int* __restrict__ tile_r0,
                            int* __restrict__ tile_nr, int* __restrict__ n_tiles) {
    if (threadIdx.x == 0) {
        int o = 0, nt = 0;
        for (int e = 0; e < NEXP; e++) {
            offsets[e] = o;
            int c = counts[e];
            for (int r = 0; r < c; r += BM) {
                tile_e[nt] = e; tile_r0[nt] = o + r;
                int nr = c - r; if (nr > BM) nr = BM;
                tile_nr[nt] = nr; nt++;
            }
            o += c;
        }
        *n_tiles = nt;
    }
}

__global__ void assign_kernel(const int* __restrict__ topk_idx,
                              const float* __restrict__ topk_w,
                              const int* __restrict__ offsets,
                              int* __restrict__ cursor,
                              int* __restrict__ row_token,
                              float* __restrict__ row_w,
                              int* __restrict__ tok_slot) {
    int t = blockIdx.x * blockDim.x + threadIdx.x;
    if (t >= T_TOKENS) return;
    for (int k = 0; k < 2; k++) {
        int e = topk_idx[t * 2 + k];
        int pos = atomicAdd(&cursor[e], 1);
        int slot = offsets[e] + pos;
        row_token[slot] = t;
        row_w[slot] = topk_w[t * 2 + k];
        tok_slot[t * 2 + k] = slot;
    }
}

__global__ void gather_kernel(const float* __restrict__ x,
                              const int* __restrict__ row_token,
                              ushort* __restrict__ xg) {
    int slot = blockIdx.x;
    int t = row_token[slot];
    const float4* src = (const float4*)(x + (size_t)t * DIM);
    ushort* dst = xg + (size_t)slot * DIM;
    int i = threadIdx.x;
    float4 v = src[i];
    ushort4 o; o.x = f2bf(v.x); o.y = f2bf(v.y); o.z = f2bf(v.z); o.w = f2bf(v.w);
    *(ushort4*)(dst + i * 4) = o;
}

// ---------------- GEMM 1: xg @ (w_gate,w_up)^T + SwiGLU -> h ----------------
// Block: 512 thr = 8 waves (4x2). Tile M=256, N=64 (G and U each), BK=32.
// A (bf16) async-staged via global_load_lds. B (fp32) reg-staged + inline cvt:
// waves 0-3 stage G, waves 4-7 stage U.
// LDS/buf: A[256][32] 16KB + G[64][32] 4KB + U[64][32] 4KB = 24KB; dbuf 48KB.
__global__ __launch_bounds__(512, 4) void gemm_gu_lds(
    const ushort* __restrict__ xg,
    const float* __restrict__ wg,
    const float* __restrict__ wu,
    const int* __restrict__ tile_e, const int* __restrict__ tile_r0,
    const int* __restrict__ tile_nr,
    ushort* __restrict__ h) {
    int tile = blockIdx.x;
    int nr = tile_nr[tile];
    if (nr == 0) return;
    int e = tile_e[tile], row0 = tile_r0[tile];
    int col0 = blockIdx.y * 64;

    __shared__ __align__(16) ushort lds[2][12288];  // bytes: A[0,16384) G[16384,20480) U[20480,24576)

    int tid = threadIdx.x;
    int lane = tid & 63;
    int wid = tid >> 6;
    int wr = wid >> 1, wc = wid & 1;

    // A staging: 1024 16B-chunks/buf; thread t handles chunks t and t+512.
    const ushort* a_src = xg + (size_t)(row0 + (tid >> 2)) * DIM + (tid & 3) * 8;
    size_t woff = (size_t)wid * 1024;               // wave-uniform LDS byte base

    // B staging: 256 threads per tensor, 8 fp32 each.
    int local = tid & 255;
    const float* b_src = (tid < 256 ? wg : wu)
        + ((size_t)e * ISZ + col0 + (local >> 2)) * DIM + (local & 3) * 8;
    int bdst = (tid < 256 ? 16384 : 20480) + (local >> 2) * 64 + (local & 3) * 16;

    float4 rb0, rb1;
    auto loadB = [&](int k) {
        rb0 = *(const float4*)(b_src + k); rb1 = *(const float4*)(b_src + k + 4);
    };
    auto stageA = [&](int b, int k) {
        char* lb = (char*)&lds[b][0];
        gl_lds16(a_src + k, lb + woff);
        gl_lds16(a_src + (size_t)128 * DIM + k, lb + woff + 8192);
    };
    auto writeB = [&](int b) {
        char* lb = (char*)&lds[b][0];
        *(bf16x8*)(lb + bdst) = cvt_frag(rb0, rb1);
    };

    int fr = lane & 15, kq = lane >> 4;
    const int a_r = wr * 64;   // wave row base (0..192)
    const int b_c = wc * 32;   // wave col base within 64-col tile

    f32x4 accG[4][2] = {};
    f32x4 accU[4][2] = {};

    loadB(0);
    stageA(0, 0);
    writeB(0);
    __syncthreads();

    int buf = 0;
    for (int k = 0; k < DIM; k += BK) {
        bool more = (k + BK < DIM);
        if (more) { loadB(k + BK); stageA(buf ^ 1, k + BK); }
        const ushort* l = &lds[buf][0];
        bf16x8 A[4], Bg[2], Bu[2];
#pragma unroll
        for (int i = 0; i < 4; i++)
            A[i] = *(const bf16x8*)(l + (a_r + i * 16 + fr) * BK + kq * 8);
#pragma unroll
        for (int j = 0; j < 2; j++) {
            Bg[j] = *(const bf16x8*)(l + 8192 + (b_c + j * 16 + fr) * BK + kq * 8);
            Bu[j] = *(const bf16x8*)(l + 10240 + (b_c + j * 16 + fr) * BK + kq * 8);
        }
#pragma unroll
        for (int i = 0; i < 4; i++)
#pragma unroll
            for (int j = 0; j < 2; j++) {
                accG[i][j] = __builtin_amdgcn_mfma_f32_16x16x32_bf16(A[i], Bg[j], accG[i][j], 0, 0, 0);
                accU[i][j] = __builtin_amdgcn_mfma_f32_16x16x32_bf16(A[i], Bu[j], accU[i][j], 0, 0, 0);
            }
        if (more) writeB(buf ^ 1);
        __syncthreads();
        buf ^= 1;
    }

    int q = lane >> 4;
#pragma unroll
    for (int i = 0; i < 4; i++) {
#pragma unroll
        for (int r = 0; r < 4; r++) {
            int lrow = a_r + i * 16 + q * 4 + r;
            if (lrow < nr) {
#pragma unroll
                for (int j = 0; j < 2; j++) {
                    float g = accG[i][j][r], u = accU[i][j][r];
                    float hv = g / (1.f + __expf(-g)) * u;
                    h[(size_t)(row0 + lrow) * ISZ + col0 + b_c + j * 16 + fr] = f2bf(hv);
                }
            }
        }
    }
}

// ---------------- GEMM 2: h @ w_down^T -> eo (plain stores) ----------------
// Block: 512 thr = 8 waves. Tile M=256 x N=64, K=2048, BK=32.
// LDS/buf: A[256][32] 16KB + B[64][32] 4KB = 20KB; dbuf 40KB.
__global__ __launch_bounds__(512, 4) void gemm_down_lds(
    const ushort* __restrict__ h,
    const float* __restrict__ wd,
    const int* __restrict__ tile_e, const int* __restrict__ tile_r0,
    const int* __restrict__ tile_nr,
    float* __restrict__ eo) {
    int tile = blockIdx.x;
    int nr = tile_nr[tile];
    if (nr == 0) return;
    int e = tile_e[tile], row0 = tile_r0[tile];
    int col0 = blockIdx.y * 64;

    __shared__ __align__(16) ushort lds[2][10240];  // bytes: A[0,16384) B[16384,20480)

    int tid = threadIdx.x;
    int lane = tid & 63;
    int wid = tid >> 6;
    int wr = wid >> 1, wc = wid & 1;

    const ushort* a_src = h + (size_t)(row0 + (tid >> 2)) * ISZ + (tid & 3) * 8;
    size_t woff = (size_t)wid * 1024;

    int local = tid & 255;
    const float* b_src = wd + ((size_t)e * DIM + col0 + (local >> 2)) * ISZ + (local & 3) * 8;
    int bdst = 16384 + (local >> 2) * 64 + (local & 3) * 16;
    bool doB = (tid < 256);

    float4 rb0, rb1;
    auto loadB = [&](int k) {
        if (doB) { rb0 = *(const float4*)(b_src + k); rb1 = *(const float4*)(b_src + k + 4); }
    };
    auto stageA = [&](int b, int k) {
        char* lb = (char*)&lds[b][0];
        gl_lds16(a_src + k, lb + woff);
        gl_lds16(a_src + (size_t)128 * ISZ + k, lb + woff + 8192);
    };
    auto writeB = [&](int b) {
        if (doB) {
            char* lb = (char*)&lds[b][0];
            *(bf16x8*)(lb + bdst) = cvt_frag(rb0, rb1);
        }
    };

    int fr = lane & 15, kq = lane >> 4;
    const int a_r = wr * 64, b_c = wc * 32;

    f32x4 acc[4][2] = {};

    loadB(0);
    stageA(0, 0);
    writeB(0);
    __syncthreads();

    int buf = 0;
    for (int k = 0; k < ISZ; k += BK) {
        bool more = (k + BK < ISZ);
        if (more) { loadB(k + BK); stageA(buf ^ 1, k + BK); }
        const ushort* l = &lds[buf][0];
        bf16x8 A[4], Bf[2];
#pragma unroll
        for (int i = 0; i < 4; i++)
            A[i] = *(const bf16x8*)(l + (a_r + i * 16 + fr) * BK + kq * 8);
#pragma unroll
        for (int j = 0; j < 2; j++)
            Bf[j] = *(const bf16x8*)(l + 8192 + (b_c + j * 16 + fr) * BK + kq * 8);
#pragma unroll
        for (int i = 0; i < 4; i++)
#pragma unroll
            for (int j = 0; j < 2; j++)
                acc[i][j] = __builtin_amdgcn_mfma_f32_16x16x32_bf16(A[i], Bf[j], acc[i][j], 0, 0, 0);
        if (more) writeB(buf ^ 1);
        __syncthreads();
        buf ^= 1;
    }

    int q = lane >> 4;
#pragma unroll
    for (int i = 0; i < 4; i++) {
#pragma unroll
        for (int r = 0; r < 4; r++) {
            int lrow = a_r + i * 16 + q * 4 + r;
            if (lrow < nr) {
                int slot = row0 + lrow;
#pragma unroll
                for (int j = 0; j < 2; j++) {
                    int col = col0 + b_c + j * 16 + fr;
                    eo[(size_t)slot * DIM + col] = acc[i][j][r];
                }
            }
        }
    }
}

// ---------------- combine: out[t] = w0*eo[s0] + w1*eo[s1] ----------------
__global__ __launch_bounds__(256) void combine_kernel(const float* __restrict__ eo,
                                                      const int* __restrict__ tok_slot,
                                                      const float* __restrict__ row_w,
                                                      float* __restrict__ out) {
    int t = blockIdx.x;
    int c = threadIdx.x * 4;
    int s0 = tok_slot[t * 2], s1 = tok_slot[t * 2 + 1];
    float w0 = row_w[s0], w1 = row_w[s1];
    float4 a = *(const float4*)(eo + (size_t)s0 * DIM + c);
    float4 b = *(const float4*)(eo + (size_t)s1 * DIM + c);
    float4 o;
    o.x = w0 * a.x + w1 * b.x;
    o.y = w0 * a.y + w1 * b.y;
    o.z = w0 * a.z + w1 * b.z;
    o.w = w0 * a.w + w1 * b.w;
    *(float4*)(out + (size_t)t * DIM + c) = o;
}

extern "C" void kernel_launch(void* const* d_in, const int* in_sizes, int n_in,
                              void* d_out, int out_size, void* d_ws, size_t ws_size,
                              hipStream_t stream) {
    const float* x      = (const float*)d_in[0];
    const float* gate_w = (const float*)d_in[1];
    const float* w_gate = (const float*)d_in[2];
    const float* w_up   = (const float*)d_in[3];
    const float* w_down = (const float*)d_in[4];

    float* out = (float*)d_out;
    float* logits_out = out + (size_t)T_TOKENS * DIM;

    char* ws = (char*)d_ws;
    int*    counts    = (int*)(ws + OFF_COUNTS);
    int*    cursor    = (int*)(ws + OFF_CURSOR);
    int*    offsets   = (int*)(ws + OFF_OFFSETS);
    int*    n_tiles   = (int*)(ws + OFF_NTILES);
    int*    tile_e    = (int*)(ws + OFF_TILE_E);
    int*    tile_r0   = (int*)(ws + OFF_TILE_R0);
    int*    tile_nr   = (int*)(ws + OFF_TILE_NR);
    int*    topk_idx  = (int*)(ws + OFF_TOPK_I);
    float*  topk_w    = (float*)(ws + OFF_TOPK_W);
    int*    row_token = (int*)(ws + OFF_ROW_T);
    float*  row_w     = (float*)(ws + OFF_ROW_W);
    int*    tok_slot  = (int*)(ws + OFF_TSLOT);
    ushort* xg        = (ushort*)(ws + OFF_XG);
    ushort* h         = (ushort*)(ws + OFF_H);
    float*  eo        = (float*)(ws + OFF_EO);

    hipMemsetAsync(d_ws, 0, 1024, stream);   // counts/cursor/offsets + tile map (dead tiles -> nr=0)

    router_kernel<<<T_TOKENS / 4, 256, 0, stream>>>(x, gate_w, logits_out, topk_idx, topk_w, counts);
    scan_kernel<<<1, 64, 0, stream>>>(counts, offsets, tile_e, tile_r0, tile_nr, n_tiles);
    assign_kernel<<<T_TOKENS / 256, 256, 0, stream>>>(topk_idx, topk_w, offsets, cursor,
                                                      row_token, row_w, tok_slot);
    gather_kernel<<<NPAIRS, 256, 0, stream>>>(x, row_token, xg);

    dim3 g1(MAXTILES, ISZ / 64);          // 24 x 32
    gemm_gu_lds<<<g1, 512, 0, stream>>>(xg, w_gate, w_up, tile_e, tile_r0, tile_nr, h);
    dim3 g2(MAXTILES, DIM / 64);          // 24 x 16
    gemm_down_lds<<<g2, 512, 0, stream>>>(h, w_down, tile_e, tile_r0, tile_nr, eo);
    combine_kernel<<<T_TOKENS, 256, 0, stream>>>(eo, tok_slot, row_w, out);
}